// Round 22
// baseline (212.313 us; speedup 1.0000x reference)
//
#include <hip/hip_runtime.h>
#include <hip/hip_bf16.h>
#include <stdint.h>

typedef unsigned short u16;
typedef __attribute__((ext_vector_type(4))) float f32x4;
typedef __attribute__((ext_vector_type(16))) float f32x16;
typedef __attribute__((ext_vector_type(8))) __bf16 bf16x8;
typedef __attribute__((ext_vector_type(2))) unsigned int u32x2;

__device__ __forceinline__ u16 f2bf(float f) {
  union { float f; uint32_t u; } x; x.f = f;
  const uint32_t u = x.u;
  return (u16)((u + 0x7fffu + ((u >> 16) & 1u)) >> 16);
}
__device__ __forceinline__ float bf2f(u16 v) {
  union { uint32_t u; float f; } x; x.u = ((uint32_t)v) << 16; return x.f;
}

// Q pre-scale: 1/sqrt(64) * log2(e), so softmax runs in exp2 domain.
#define QSCALE 0.1803368801111244f

// ------------------------------------------------------- fp32 -> bf16 cast
__global__ void cvt_f32_bf16(const float* __restrict__ in, u16* __restrict__ out,
                             int n) {
  const int i = (blockIdx.x * blockDim.x + threadIdx.x) * 4;
  if (i < n) {
    const float4 v = *(const float4*)(in + i);
    ushort4 o;
    o.x = f2bf(v.x); o.y = f2bf(v.y); o.z = f2bf(v.z); o.w = f2bf(v.w);
    *(ushort4*)(out + i) = o;
  }
}

// ------------------------- transpose + cast: f32 [R][Cc] -> bf16 [Cc][R]
__global__ void transpose_cvt(const float* __restrict__ in, u16* __restrict__ out,
                              int R, int Cc) {
  __shared__ u16 tile[64][66];
  const int tx = threadIdx.x, ty = threadIdx.y;
  const int c0 = blockIdx.x * 64, r0 = blockIdx.y * 64;
#pragma unroll
  for (int i = 0; i < 4; ++i)
    tile[ty + i * 16][tx] = f2bf(in[(size_t)(r0 + ty + i * 16) * Cc + c0 + tx]);
  __syncthreads();
#pragma unroll
  for (int i = 0; i < 4; ++i)
    out[(size_t)(c0 + ty + i * 16) * R + r0 + tx] = tile[tx][ty + i * 16];
}

// ---------------- per-head V transpose: [2048][64] -> [64][2048] (bf16)
__global__ void transpose_v(const u16* __restrict__ V, u16* __restrict__ VT) {
  __shared__ u16 tile[64][66];
  const int tx = threadIdx.x, ty = threadIdx.y;
  const int r0 = blockIdx.x * 64;                 // t-tile
  const size_t ho = (size_t)blockIdx.y * 2048 * 64;
  const u16* in = V + ho;
  u16* out = VT + ho;
#pragma unroll
  for (int i = 0; i < 4; ++i)
    tile[ty + i * 16][tx] = in[(size_t)(r0 + ty + i * 16) * 64 + tx];
  __syncthreads();
#pragma unroll
  for (int i = 0; i < 4; ++i)
    out[(size_t)(ty + i * 16) * 2048 + r0 + tx] = tile[tx][ty + i * 16];
}

// ------------------------------------------------ 8-phase 128x256 GEMM
// (R17 schedule: conflicts 0, T2 source-swizzle, counted vmcnt(4) at ph4/8.)
// MODE 1: QKV scatter epilogue (Q pre-scaled).  MODE 0: fp32 linear out.
template <int MODE>
__global__ __launch_bounds__(512, 2) void gemm8p(
    const u16* __restrict__ A, const u16* __restrict__ BT,
    u16* __restrict__ Qo, u16* __restrict__ Ko, u16* __restrict__ Vo,
    float* __restrict__ out, int Nout, int K) {
  __shared__ u16 LA[2][128 * 64];       // [dbuf] A rows 0-127
  __shared__ u16 LB[2][2][128 * 64];    // [dbuf][half] B N-rows 0-127/128-255
  const int tid = threadIdx.x, wid = tid >> 6, lane = tid & 63;
  const int wm = wid >> 2, wn = wid & 3;
  const int l15 = lane & 15, l4 = lane >> 4;
  const int bn = blockIdx.x, bm = blockIdx.y;

  const u16* Atile = A + (size_t)bm * 128 * K;
  const u16* Btile = BT + (size_t)bn * 256 * K;

  f32x4 acc[4][4] = {};
  bf16x8 aF[4][2], bF[4][2];
  const int cb = wid * 64 + lane;

#define SB8() __builtin_amdgcn_sched_barrier(0)
#define BAR8() { SB8(); __builtin_amdgcn_s_barrier(); SB8(); }
#define VW4() { SB8(); asm volatile("s_waitcnt vmcnt(4)" ::: "memory"); SB8(); }
#define STGU(dst, srcbase) { \
    const u16* s0_ = (srcbase); \
    _Pragma("unroll") for (int j_ = 0; j_ < 2; ++j_) { \
      const int c_ = j_ * 512 + cb; \
      const int r_ = c_ >> 3; \
      const int g_ = (c_ & 7) ^ (r_ & 7); \
      __builtin_amdgcn_global_load_lds( \
          (const __attribute__((address_space(1))) uint32_t*)(s0_ + (size_t)r_ * K + g_ * 8), \
          (__attribute__((address_space(3))) uint32_t*)(&(dst)[(j_ * 512 + wid * 64) * 8]), 16, 0, 0); \
    } }
#define STG_A(d, kt) STGU(LA[d], Atile + (size_t)(kt) * 64)
#define STG_B(d, h, kt) STGU(LB[d][h], Btile + (size_t)(h) * 128 * K + (size_t)(kt) * 64)
#define LD_A(d) { \
    _Pragma("unroll") for (int m_ = 0; m_ < 4; ++m_) \
    _Pragma("unroll") for (int k_ = 0; k_ < 2; ++k_) \
      aF[m_][k_] = *(const bf16x8*)&LA[d][(wm * 64 + m_ * 16 + l15) * 64 + (((k_ * 4 + l4) ^ (l15 & 7)) * 8)]; }
#define LD_B(d, nbase) { \
    _Pragma("unroll") for (int n_ = 0; n_ < 2; ++n_) \
    _Pragma("unroll") for (int k_ = 0; k_ < 2; ++k_) \
      bF[(nbase) + n_][k_] = *(const bf16x8*)&LB[d][wn >> 1][((wn & 1) * 64 + ((nbase) + n_) * 16 + l15) * 64 + (((k_ * 4 + l4) ^ (l15 & 7)) * 8)]; }
#define MQ(MS, NS) { __builtin_amdgcn_s_setprio(1); \
    _Pragma("unroll") for (int m_ = 0; m_ < 2; ++m_) \
    _Pragma("unroll") for (int n_ = 0; n_ < 2; ++n_) \
    _Pragma("unroll") for (int kk_ = 0; kk_ < 2; ++kk_) \
      acc[(MS) * 2 + m_][(NS) * 2 + n_] = __builtin_amdgcn_mfma_f32_16x16x32_bf16( \
          aF[(MS) * 2 + m_][kk_], bF[(NS) * 2 + n_][kk_], acc[(MS) * 2 + m_][(NS) * 2 + n_], 0, 0, 0); \
    __builtin_amdgcn_s_setprio(0); }

  STG_A(0, 0); STG_B(0, 0, 0); STG_B(0, 1, 0);
  STG_A(1, 1); STG_B(1, 0, 1);
  VW4();
  BAR8();

  const int nkt = K >> 6;  // 16
  for (int it = 0; it < nkt / 2; ++it) {
    const int t1 = 2 * it + 1;
    const int t2 = (2 * it + 2 < nkt) ? 2 * it + 2 : nkt - 1;
    const int t3 = (2 * it + 3 < nkt) ? 2 * it + 3 : nkt - 1;
    LD_A(0); LD_B(0, 0);
    STG_B(1, 1, t1);
    BAR8(); MQ(0, 0); BAR8();
    STG_A(0, t2);
    BAR8(); MQ(1, 0); BAR8();
    LD_B(0, 2);
    BAR8(); MQ(0, 1); BAR8();
    STG_B(0, 0, t2);
    VW4();
    BAR8(); MQ(1, 1); BAR8();
    LD_A(1); LD_B(1, 0);
    STG_B(0, 1, t2);
    BAR8(); MQ(0, 0); BAR8();
    STG_A(1, t3);
    BAR8(); MQ(1, 0); BAR8();
    LD_B(1, 2);
    BAR8(); MQ(0, 1); BAR8();
    STG_B(1, 0, t3);
    VW4();
    BAR8(); MQ(1, 1); BAR8();
  }
  asm volatile("s_waitcnt vmcnt(0)" ::: "memory");

  const int row0 = bm * 128 + wm * 64;
  const int col0 = bn * 256 + wn * 64;
#pragma unroll
  for (int m = 0; m < 4; ++m) {
#pragma unroll
    for (int n = 0; n < 4; ++n) {
#pragma unroll
      for (int jj = 0; jj < 4; ++jj) {
        const int row = row0 + m * 16 + l4 * 4 + jj;
        const int col = col0 + n * 16 + l15;
        if (MODE == 1) {
          const int sec = col >> 10, c = col & 1023;
          const int h = c >> 6, d = c & 63;
          const int b = row >> 11, t = row & 2047;
          float av = acc[m][n][jj];
          if (sec == 0) av *= QSCALE;
          u16* dst = (sec == 0) ? Qo : (sec == 1) ? Ko : Vo;
          dst[(((size_t)(b * 16 + h)) * 2048 + t) * 64 + d] = f2bf(av);
        } else {
          out[(size_t)row * Nout + col] = acc[m][n][jj];  // fp32 output
        }
      }
    }
  }
#undef SB8
#undef BAR8
#undef VW4
#undef STGU
#undef STG_A
#undef STG_B
#undef LD_A
#undef LD_B
#undef MQ
}

// ---------------------------------------------------------------- attention
// Split-KV: block = (qt, half); half 0 does kv tiles [0,qt+1), half 1 does
// [qt+1, 2qt+2) -- both qt+1 tiles. Grid (32,64) = 2048 blocks; LDS 18.4KB
// single-buffer -> 8 blocks/CU. 5-bit XOR masks {0,30,10,20,6,24,12,18}
// (per-bit balanced) make every CU's 8 co-resident works sum to 68 tiles,
// fixing the causal tail (R21: occupancy 26%, CU busy ~32 units vs 17 avg).
// Each block writes self-normalized O (bf16) + (m,l) fp32; attn_combine
// merges. Fully-masked hi-halves get weight 2^(m-...)=0 -> safe.
__global__ __launch_bounds__(256, 4) void attn_fwd(
    const u16* __restrict__ Qp, const u16* __restrict__ Kp,
    const u16* __restrict__ VTp, u16* __restrict__ OpL,
    u16* __restrict__ OpH, float2* __restrict__ ml) {
  constexpr int DP = 72;
  constexpr float THR = 11.0f;
  __shared__ u16 Ks[64 * DP];
  __shared__ u16 Vt[64 * DP];

  const uint64_t PACK = 0ULL | 30ULL << 5 | 10ULL << 10 | 20ULL << 15 |
                        6ULL << 20 | 24ULL << 25 | 12ULL << 30 | 18ULL << 35;
  const int mask5 = (int)((PACK >> (5 * ((blockIdx.y >> 3) & 7))) & 31u);
  const int wxr = (int)blockIdx.x ^ mask5;   // bijective per bh
  const int qt = wxr >> 1, half = wxr & 1;
  const int bh = blockIdx.y;
  const int tid = threadIdx.x, lane = tid & 63;
  const int wid = tid >> 6;
  const int l31 = lane & 31, hb = lane >> 5;

  const size_t head_off = (size_t)bh * 2048 * 64;
  const u16* Kh = Kp + head_off;
  const u16* VTh = VTp + head_off;

  const int qg = qt * 128 + wid * 32 + l31;
  const u16* Qrow = Qp + head_off + (size_t)qg * 64;

  bf16x8 qf[4];
#pragma unroll
  for (int d = 0; d < 4; ++d)
    qf[d] = *(const bf16x8*)(Qrow + d * 16 + hb * 8);

  bf16x8 ones;
#pragma unroll
  for (int i = 0; i < 8; ++i) ones[i] = (__bf16)1.0f;

  float m_ = -1e30f;
  f32x16 oacc[2] = {};
  f32x16 lacc = {};

  const int sr = tid >> 3;
  const int sc = (tid & 7) * 8;

  bf16x8 kreg[2], vreg[2];
  auto kvload = [&](int kt) {
#pragma unroll
    for (int it = 0; it < 2; ++it) {
      const int r = sr + it * 32;
      kreg[it] = *(const bf16x8*)(Kh + (size_t)(kt * 64 + r) * 64 + sc);
      vreg[it] = *(const bf16x8*)(VTh + (size_t)r * 2048 + kt * 64 + sc);
    }
  };
  auto kvwrite = [&]() {
#pragma unroll
    for (int it = 0; it < 2; ++it) {
      const int r = sr + it * 32;
      *(bf16x8*)&Ks[r * DP + sc] = kreg[it];
      *(bf16x8*)&Vt[r * DP + sc] = vreg[it];
    }
  };

  const int k0 = half ? (qt + 1) : 0;
  const int k1 = half ? (2 * qt + 2) : (qt + 1);

  kvload(k0);
  for (int kt = k0; kt < k1; ++kt) {
    __syncthreads();  // previous tile's LDS consumers done
    kvwrite();
    if (kt + 1 < k1) kvload(kt + 1);  // issue early; hides under compute
    __syncthreads();

    const bool diag = (kt >= 2 * qt);

#pragma unroll
    for (int kb2 = 0; kb2 < 2; ++kb2) {
      f32x16 s = {};
      __builtin_amdgcn_s_setprio(1);
#pragma unroll
      for (int d = 0; d < 4; ++d) {
        const bf16x8 kf = *(const bf16x8*)&Ks[(kb2 * 32 + l31) * DP + d * 16 + hb * 8];
        s = __builtin_amdgcn_mfma_f32_32x32x16_bf16(kf, qf[d], s, 0, 0, 0);
      }
      __builtin_amdgcn_s_setprio(0);

      if (diag) {
        const int kbase = kt * 64 + kb2 * 32 + hb * 4;
#pragma unroll
        for (int r = 0; r < 16; ++r) {
          const int koff = (r & 3) + 8 * (r >> 2);
          if (kbase + koff > qg) s[r] = -1e30f;
        }
      }

      float pmax = s[0];
#pragma unroll
      for (int r = 1; r < 16; ++r) pmax = fmaxf(pmax, s[r]);
      if (!__all(pmax - m_ <= THR)) {
        const float fm = fmaxf(pmax, __shfl_xor(pmax, 32));
        const float mnew = fmaxf(m_, fm);
        const float alpha = __builtin_exp2f(m_ - mnew);
        m_ = mnew;
#pragma unroll
        for (int r = 0; r < 16; ++r) lacc[r] *= alpha;
#pragma unroll
        for (int nb = 0; nb < 2; ++nb)
#pragma unroll
          for (int r = 0; r < 16; ++r) oacc[nb][r] *= alpha;
      }
#pragma unroll
      for (int r = 0; r < 16; ++r)
        s[r] = __builtin_exp2f(s[r] - m_);

      bf16x8 pb[2];
#pragma unroll
      for (int st = 0; st < 2; ++st) {
        uint32_t x0, x1, y0, y1;
        asm("v_cvt_pk_bf16_f32 %0, %1, %2" : "=v"(x0) : "v"(s[8 * st + 0]), "v"(s[8 * st + 1]));
        asm("v_cvt_pk_bf16_f32 %0, %1, %2" : "=v"(x1) : "v"(s[8 * st + 2]), "v"(s[8 * st + 3]));
        asm("v_cvt_pk_bf16_f32 %0, %1, %2" : "=v"(y0) : "v"(s[8 * st + 4]), "v"(s[8 * st + 5]));
        asm("v_cvt_pk_bf16_f32 %0, %1, %2" : "=v"(y1) : "v"(s[8 * st + 6]), "v"(s[8 * st + 7]));
        const u32x2 r0 = __builtin_amdgcn_permlane32_swap(x0, y0, false, false);
        const u32x2 r1 = __builtin_amdgcn_permlane32_swap(x1, y1, false, false);
        union { uint32_t w[4]; bf16x8 v; } u;
        u.w[0] = r0[0]; u.w[1] = r1[0]; u.w[2] = r0[1]; u.w[3] = r1[1];
        pb[st] = u.v;
      }

      __builtin_amdgcn_s_setprio(1);
#pragma unroll
      for (int st = 0; st < 2; ++st) {
        lacc = __builtin_amdgcn_mfma_f32_32x32x16_bf16(ones, pb[st], lacc, 0, 0, 0);
#pragma unroll
        for (int nb = 0; nb < 2; ++nb) {
          const bf16x8 vf = *(const bf16x8*)&Vt[(nb * 32 + l31) * DP + kb2 * 32 + st * 16 + hb * 8];
          oacc[nb] = __builtin_amdgcn_mfma_f32_32x32x16_bf16(vf, pb[st], oacc[nb], 0, 0, 0);
        }
      }
      __builtin_amdgcn_s_setprio(0);
    }
  }

  // self-normalized partial O (bf16) + (m, l) fp32
  const size_t g = (size_t)bh * 2048 + qg;
  const float inv = 1.0f / lacc[0];
  u16* Orow = (half ? OpH : OpL) + g * 64;
#pragma unroll
  for (int nb = 0; nb < 2; ++nb) {
#pragma unroll
    for (int gg = 0; gg < 4; ++gg) {
      ushort4 o;
      o.x = f2bf(oacc[nb][4 * gg + 0] * inv);
      o.y = f2bf(oacc[nb][4 * gg + 1] * inv);
      o.z = f2bf(oacc[nb][4 * gg + 2] * inv);
      o.w = f2bf(oacc[nb][4 * gg + 3] * inv);
      *(ushort4*)(Orow + nb * 32 + gg * 8 + hb * 4) = o;
    }
  }
  if (hb == 0) {
    float2 v; v.x = m_; v.y = lacc[0];
    ml[(size_t)half * 131072 + g] = v;
  }
}

// -------------------------------------------------- combine split-KV halves
// Y = (l1*w1*O1 + l2*w2*O2) / (l1*w1 + l2*w2), wi = 2^(mi - max(m1,m2)).
// Rows g = bh*2048 + t; output scattered to Y[(b*2048+t)*1024 + h*64 + d].
__global__ __launch_bounds__(256) void attn_combine(
    const u16* __restrict__ OpL, const u16* __restrict__ OpH,
    const float2* __restrict__ ml, u16* __restrict__ Yf) {
  const int tid = threadIdx.x;
  const size_t g = (size_t)blockIdx.x * 64 + (tid >> 2);
  const int c = (tid & 3) * 16;
  const float2 a = ml[g], bq = ml[131072 + g];
  const float m = fmaxf(a.x, bq.x);
  const float w1 = __builtin_exp2f(a.x - m) * a.y;
  const float w2 = __builtin_exp2f(bq.x - m) * bq.y;
  const float den = 1.0f / (w1 + w2);
  const float c1 = w1 * den, c2 = w2 * den;

  union { ushort4 s[2]; bf16x8 v; } l0, l1, h0, h1, o0, o1;
  l0.v = *(const bf16x8*)(OpL + g * 64 + c);
  l1.v = *(const bf16x8*)(OpL + g * 64 + c + 8);
  h0.v = *(const bf16x8*)(OpH + g * 64 + c);
  h1.v = *(const bf16x8*)(OpH + g * 64 + c + 8);
  const u16* lu = (const u16*)&l0; const u16* hu = (const u16*)&h0;
  u16* ou = (u16*)&o0;
#pragma unroll
  for (int i = 0; i < 8; ++i) ou[i] = f2bf(c1 * bf2f(lu[i]) + c2 * bf2f(hu[i]));
  const u16* lu1 = (const u16*)&l1; const u16* hu1 = (const u16*)&h1;
  u16* ou1 = (u16*)&o1;
#pragma unroll
  for (int i = 0; i < 8; ++i) ou1[i] = f2bf(c1 * bf2f(lu1[i]) + c2 * bf2f(hu1[i]));

  const int bh = (int)(g >> 11), t = (int)(g & 2047);
  const int b = bh >> 4, h = bh & 15;
  u16* dst = Yf + ((size_t)(b * 2048 + t)) * 1024 + h * 64 + c;
  *(bf16x8*)dst = o0.v;
  *(bf16x8*)(dst + 8) = o1.v;
}

// ---------------------------------------------------------------- launch
extern "C" void kernel_launch(void* const* d_in, const int* in_sizes, int n_in,
                              void* d_out, int out_size, void* d_ws,
                              size_t ws_size, hipStream_t stream) {
  const float* x = (const float*)d_in[0];       // [4,2048,1024] fp32
  const float* w_qkv = (const float*)d_in[1];   // [1024,3072] fp32
  const float* w_proj = (const float*)d_in[2];  // [1024,1024] fp32
  float* out = (float*)d_out;                   // [4,2048,1024] fp32

  char* ws = (char*)d_ws;
  // region 0 (16MB): xb (QKV A-input) -> VTw (V^T) -> Yfinal (combine out)
  u16* xb = (u16*)ws;
  u16* VTw = (u16*)ws;
  u16* Yf = (u16*)ws;
  // region 16MB (6MB): wqkvT -> ml (2x131072 float2 = 2MB)
  u16* wqkvT = (u16*)(ws + 16777216);
  float2* mlw = (float2*)(ws + 16777216);
  u16* wprojT = (u16*)(ws + 23068672);         // live until proj
  u16* Qw = (u16*)(ws + 25165824);             // [B,H,T,D]
  u16* Kw = (u16*)(ws + 41943040);
  u16* Vw = (u16*)(ws + 58720256);             // V row-major -> O_part_hi
  u16* OpH = (u16*)(ws + 58720256);
  u16* Yw = (u16*)(ws + 75497472);             // O_part_lo
  u16* OpL = (u16*)(ws + 75497472);
  if (ws_size < 92274688) return;

  cvt_f32_bf16<<<dim3(8192), dim3(256), 0, stream>>>(x, xb, 8388608);

  dim3 tb(64, 16);
  transpose_cvt<<<dim3(48, 16), tb, 0, stream>>>(w_qkv, wqkvT, 1024, 3072);
  transpose_cvt<<<dim3(16, 16), tb, 0, stream>>>(w_proj, wprojT, 1024, 1024);

  gemm8p<1><<<dim3(12, 64), dim3(512), 0, stream>>>(
      xb, wqkvT, Qw, Kw, Vw, (float*)nullptr, 0, 1024);

  // xb dead; build VT in its place.
  transpose_v<<<dim3(32, 64), tb, 0, stream>>>(Vw, VTw);

  // wqkvT dead -> ml; Vw dead (VT built) -> OpH; Yw -> OpL.
  attn_fwd<<<dim3(32, 64), dim3(256), 0, stream>>>(Qw, Kw, VTw, OpL, OpH, mlw);

  // VTw dead after attn -> Yfinal.
  attn_combine<<<dim3(2048), dim3(256), 0, stream>>>(OpL, OpH, mlw, Yf);

  gemm8p<0><<<dim3(4, 64), dim3(512), 0, stream>>>(
      Yf, wprojT, (u16*)nullptr, (u16*)nullptr, (u16*)nullptr, out, 1024, 1024);
}

// Round 23
// 194.894 us; speedup vs baseline: 1.0894x; 1.0894x over previous
//
#include <hip/hip_runtime.h>
#include <hip/hip_bf16.h>
#include <stdint.h>

typedef unsigned short u16;
typedef __attribute__((ext_vector_type(4))) float f32x4;
typedef __attribute__((ext_vector_type(16))) float f32x16;
typedef __attribute__((ext_vector_type(8))) __bf16 bf16x8;
typedef __attribute__((ext_vector_type(2))) unsigned int u32x2;

__device__ __forceinline__ u16 f2bf(float f) {
  union { float f; uint32_t u; } x; x.f = f;
  const uint32_t u = x.u;
  return (u16)((u + 0x7fffu + ((u >> 16) & 1u)) >> 16);
}

// Q pre-scale: 1/sqrt(64) * log2(e), so softmax runs in exp2 domain.
#define QSCALE 0.1803368801111244f

// ------------------------------------------------------- fp32 -> bf16 cast
__global__ void cvt_f32_bf16(const float* __restrict__ in, u16* __restrict__ out,
                             int n) {
  const int i = (blockIdx.x * blockDim.x + threadIdx.x) * 4;
  if (i < n) {
    const float4 v = *(const float4*)(in + i);
    ushort4 o;
    o.x = f2bf(v.x); o.y = f2bf(v.y); o.z = f2bf(v.z); o.w = f2bf(v.w);
    *(ushort4*)(out + i) = o;
  }
}

// ------------------------- transpose + cast: f32 [R][Cc] -> bf16 [Cc][R]
__global__ void transpose_cvt(const float* __restrict__ in, u16* __restrict__ out,
                              int R, int Cc) {
  __shared__ u16 tile[64][66];
  const int tx = threadIdx.x, ty = threadIdx.y;
  const int c0 = blockIdx.x * 64, r0 = blockIdx.y * 64;
#pragma unroll
  for (int i = 0; i < 4; ++i)
    tile[ty + i * 16][tx] = f2bf(in[(size_t)(r0 + ty + i * 16) * Cc + c0 + tx]);
  __syncthreads();
#pragma unroll
  for (int i = 0; i < 4; ++i)
    out[(size_t)(c0 + ty + i * 16) * R + r0 + tx] = tile[tx][ty + i * 16];
}

// ---------------- per-head V transpose: [2048][64] -> [64][2048] (bf16)
__global__ void transpose_v(const u16* __restrict__ V, u16* __restrict__ VT) {
  __shared__ u16 tile[64][66];
  const int tx = threadIdx.x, ty = threadIdx.y;
  const int r0 = blockIdx.x * 64;                 // t-tile
  const size_t ho = (size_t)blockIdx.y * 2048 * 64;
  const u16* in = V + ho;
  u16* out = VT + ho;
#pragma unroll
  for (int i = 0; i < 4; ++i)
    tile[ty + i * 16][tx] = in[(size_t)(r0 + ty + i * 16) * 64 + tx];
  __syncthreads();
#pragma unroll
  for (int i = 0; i < 4; ++i)
    out[(size_t)(ty + i * 16) * 2048 + r0 + tx] = tile[tx][ty + i * 16];
}

// ------------------------------------------------ 8-phase 128x256 GEMM
// (R17 schedule: conflicts 0, T2 source-swizzle, counted vmcnt(4) at ph4/8.)
// MODE 1: QKV scatter epilogue (Q pre-scaled).  MODE 0: fp32 linear out
// with stride Nout (proj: grid (4,64) = 256 blocks = exactly 1 round).
template <int MODE>
__global__ __launch_bounds__(512, 2) void gemm8p(
    const u16* __restrict__ A, const u16* __restrict__ BT,
    u16* __restrict__ Qo, u16* __restrict__ Ko, u16* __restrict__ Vo,
    float* __restrict__ out, int Nout, int K) {
  __shared__ u16 LA[2][128 * 64];       // [dbuf] A rows 0-127
  __shared__ u16 LB[2][2][128 * 64];    // [dbuf][half] B N-rows 0-127/128-255
  const int tid = threadIdx.x, wid = tid >> 6, lane = tid & 63;
  const int wm = wid >> 2, wn = wid & 3;
  const int l15 = lane & 15, l4 = lane >> 4;
  const int bn = blockIdx.x, bm = blockIdx.y;

  const u16* Atile = A + (size_t)bm * 128 * K;
  const u16* Btile = BT + (size_t)bn * 256 * K;

  f32x4 acc[4][4] = {};
  bf16x8 aF[4][2], bF[4][2];
  const int cb = wid * 64 + lane;

#define SB8() __builtin_amdgcn_sched_barrier(0)
#define BAR8() { SB8(); __builtin_amdgcn_s_barrier(); SB8(); }
#define VW4() { SB8(); asm volatile("s_waitcnt vmcnt(4)" ::: "memory"); SB8(); }
#define STGU(dst, srcbase) { \
    const u16* s0_ = (srcbase); \
    _Pragma("unroll") for (int j_ = 0; j_ < 2; ++j_) { \
      const int c_ = j_ * 512 + cb; \
      const int r_ = c_ >> 3; \
      const int g_ = (c_ & 7) ^ (r_ & 7); \
      __builtin_amdgcn_global_load_lds( \
          (const __attribute__((address_space(1))) uint32_t*)(s0_ + (size_t)r_ * K + g_ * 8), \
          (__attribute__((address_space(3))) uint32_t*)(&(dst)[(j_ * 512 + wid * 64) * 8]), 16, 0, 0); \
    } }
#define STG_A(d, kt) STGU(LA[d], Atile + (size_t)(kt) * 64)
#define STG_B(d, h, kt) STGU(LB[d][h], Btile + (size_t)(h) * 128 * K + (size_t)(kt) * 64)
#define LD_A(d) { \
    _Pragma("unroll") for (int m_ = 0; m_ < 4; ++m_) \
    _Pragma("unroll") for (int k_ = 0; k_ < 2; ++k_) \
      aF[m_][k_] = *(const bf16x8*)&LA[d][(wm * 64 + m_ * 16 + l15) * 64 + (((k_ * 4 + l4) ^ (l15 & 7)) * 8)]; }
#define LD_B(d, nbase) { \
    _Pragma("unroll") for (int n_ = 0; n_ < 2; ++n_) \
    _Pragma("unroll") for (int k_ = 0; k_ < 2; ++k_) \
      bF[(nbase) + n_][k_] = *(const bf16x8*)&LB[d][wn >> 1][((wn & 1) * 64 + ((nbase) + n_) * 16 + l15) * 64 + (((k_ * 4 + l4) ^ (l15 & 7)) * 8)]; }
#define MQ(MS, NS) { __builtin_amdgcn_s_setprio(1); \
    _Pragma("unroll") for (int m_ = 0; m_ < 2; ++m_) \
    _Pragma("unroll") for (int n_ = 0; n_ < 2; ++n_) \
    _Pragma("unroll") for (int kk_ = 0; kk_ < 2; ++kk_) \
      acc[(MS) * 2 + m_][(NS) * 2 + n_] = __builtin_amdgcn_mfma_f32_16x16x32_bf16( \
          aF[(MS) * 2 + m_][kk_], bF[(NS) * 2 + n_][kk_], acc[(MS) * 2 + m_][(NS) * 2 + n_], 0, 0, 0); \
    __builtin_amdgcn_s_setprio(0); }

  STG_A(0, 0); STG_B(0, 0, 0); STG_B(0, 1, 0);
  STG_A(1, 1); STG_B(1, 0, 1);
  VW4();
  BAR8();

  const int nkt = K >> 6;  // 16
  for (int it = 0; it < nkt / 2; ++it) {
    const int t1 = 2 * it + 1;
    const int t2 = (2 * it + 2 < nkt) ? 2 * it + 2 : nkt - 1;
    const int t3 = (2 * it + 3 < nkt) ? 2 * it + 3 : nkt - 1;
    LD_A(0); LD_B(0, 0);
    STG_B(1, 1, t1);
    BAR8(); MQ(0, 0); BAR8();
    STG_A(0, t2);
    BAR8(); MQ(1, 0); BAR8();
    LD_B(0, 2);
    BAR8(); MQ(0, 1); BAR8();
    STG_B(0, 0, t2);
    VW4();
    BAR8(); MQ(1, 1); BAR8();
    LD_A(1); LD_B(1, 0);
    STG_B(0, 1, t2);
    BAR8(); MQ(0, 0); BAR8();
    STG_A(1, t3);
    BAR8(); MQ(1, 0); BAR8();
    LD_B(1, 2);
    BAR8(); MQ(0, 1); BAR8();
    STG_B(1, 0, t3);
    VW4();
    BAR8(); MQ(1, 1); BAR8();
  }
  asm volatile("s_waitcnt vmcnt(0)" ::: "memory");

  const int row0 = bm * 128 + wm * 64;
  const int col0 = bn * 256 + wn * 64;
#pragma unroll
  for (int m = 0; m < 4; ++m) {
#pragma unroll
    for (int n = 0; n < 4; ++n) {
#pragma unroll
      for (int jj = 0; jj < 4; ++jj) {
        const int row = row0 + m * 16 + l4 * 4 + jj;
        const int col = col0 + n * 16 + l15;
        if (MODE == 1) {
          const int sec = col >> 10, c = col & 1023;
          const int h = c >> 6, d = c & 63;
          const int b = row >> 11, t = row & 2047;
          float av = acc[m][n][jj];
          if (sec == 0) av *= QSCALE;
          u16* dst = (sec == 0) ? Qo : (sec == 1) ? Ko : Vo;
          dst[(((size_t)(b * 16 + h)) * 2048 + t) * 64 + d] = f2bf(av);
        } else {
          out[(size_t)row * Nout + col] = acc[m][n][jj];  // fp32 output
        }
      }
    }
  }
#undef SB8
#undef BAR8
#undef VW4
#undef STGU
#undef STG_A
#undef STG_B
#undef LD_A
#undef LD_B
#undef MQ
}

// ---------------------------------------------------------------- attention
// R14 structure + l-via-MFMA (R20/R21 measured best: ~88 us).
__global__ __launch_bounds__(256, 4) void attn_fwd(const u16* __restrict__ Qp,
                                                   const u16* __restrict__ Kp,
                                                   const u16* __restrict__ VTp,
                                                   u16* __restrict__ Y) {
  constexpr int DP = 72;
  constexpr float THR = 11.0f;
  __shared__ u16 Ks[2][64 * DP];
  __shared__ u16 Vt[2][64 * DP];

  const int xorm = (int)((0x0A050F00u >> ((blockIdx.y >> 4) * 8)) & 15u);
  const int qt = (int)blockIdx.x ^ xorm;
  const int bh = blockIdx.y;
  const int b = bh >> 4, h = bh & 15;
  const int tid = threadIdx.x, lane = tid & 63;
  const int wid = tid >> 6;
  const int l31 = lane & 31, hb = lane >> 5;

  const size_t head_off = (size_t)bh * 2048 * 64;
  const u16* Kh = Kp + head_off;
  const u16* VTh = VTp + head_off;

  const int qg = qt * 128 + wid * 32 + l31;
  const u16* Qrow = Qp + head_off + (size_t)qg * 64;

  bf16x8 qf[4];
#pragma unroll
  for (int d = 0; d < 4; ++d)
    qf[d] = *(const bf16x8*)(Qrow + d * 16 + hb * 8);

  bf16x8 ones;
#pragma unroll
  for (int i = 0; i < 8; ++i) ones[i] = (__bf16)1.0f;

  float m_ = -1e30f;
  f32x16 oacc[2] = {};
  f32x16 lacc = {};

  const int sr = tid >> 3;
  const int sc = (tid & 7) * 8;

  bf16x8 kreg[2], vreg[2];
  auto kvload = [&](int kt) {
#pragma unroll
    for (int it = 0; it < 2; ++it) {
      const int r = sr + it * 32;
      kreg[it] = *(const bf16x8*)(Kh + (size_t)(kt * 64 + r) * 64 + sc);
      vreg[it] = *(const bf16x8*)(VTh + (size_t)r * 2048 + kt * 64 + sc);
    }
  };
  auto kvwrite = [&](int buf) {
#pragma unroll
    for (int it = 0; it < 2; ++it) {
      const int r = sr + it * 32;
      *(bf16x8*)&Ks[buf][r * DP + sc] = kreg[it];
      *(bf16x8*)&Vt[buf][r * DP + sc] = vreg[it];
    }
  };

  kvload(0);
  kvwrite(0);
  __syncthreads();

  const int nt = 2 * qt + 2;
  for (int kt = 0; kt < nt; ++kt) {
    const int cur = kt & 1;
    const bool havenext = (kt + 1 < nt);
    if (havenext) kvload(kt + 1);

    const bool diag = (kt >= 2 * qt);

#pragma unroll
    for (int kb2 = 0; kb2 < 2; ++kb2) {
      f32x16 s = {};
      __builtin_amdgcn_s_setprio(1);
#pragma unroll
      for (int d = 0; d < 4; ++d) {
        const bf16x8 kf = *(const bf16x8*)&Ks[cur][(kb2 * 32 + l31) * DP + d * 16 + hb * 8];
        s = __builtin_amdgcn_mfma_f32_32x32x16_bf16(kf, qf[d], s, 0, 0, 0);
      }
      __builtin_amdgcn_s_setprio(0);

      if (diag) {
        const int kbase = kt * 64 + kb2 * 32 + hb * 4;
#pragma unroll
        for (int r = 0; r < 16; ++r) {
          const int koff = (r & 3) + 8 * (r >> 2);
          if (kbase + koff > qg) s[r] = -1e30f;
        }
      }

      float pmax = s[0];
#pragma unroll
      for (int r = 1; r < 16; ++r) pmax = fmaxf(pmax, s[r]);
      if (!__all(pmax - m_ <= THR)) {
        const float fm = fmaxf(pmax, __shfl_xor(pmax, 32));
        const float mnew = fmaxf(m_, fm);
        const float alpha = __builtin_exp2f(m_ - mnew);
        m_ = mnew;
#pragma unroll
        for (int r = 0; r < 16; ++r) lacc[r] *= alpha;
#pragma unroll
        for (int nb = 0; nb < 2; ++nb)
#pragma unroll
          for (int r = 0; r < 16; ++r) oacc[nb][r] *= alpha;
      }
#pragma unroll
      for (int r = 0; r < 16; ++r)
        s[r] = __builtin_exp2f(s[r] - m_);

      bf16x8 pb[2];
#pragma unroll
      for (int st = 0; st < 2; ++st) {
        uint32_t x0, x1, y0, y1;
        asm("v_cvt_pk_bf16_f32 %0, %1, %2" : "=v"(x0) : "v"(s[8 * st + 0]), "v"(s[8 * st + 1]));
        asm("v_cvt_pk_bf16_f32 %0, %1, %2" : "=v"(x1) : "v"(s[8 * st + 2]), "v"(s[8 * st + 3]));
        asm("v_cvt_pk_bf16_f32 %0, %1, %2" : "=v"(y0) : "v"(s[8 * st + 4]), "v"(s[8 * st + 5]));
        asm("v_cvt_pk_bf16_f32 %0, %1, %2" : "=v"(y1) : "v"(s[8 * st + 6]), "v"(s[8 * st + 7]));
        const u32x2 r0 = __builtin_amdgcn_permlane32_swap(x0, y0, false, false);
        const u32x2 r1 = __builtin_amdgcn_permlane32_swap(x1, y1, false, false);
        union { uint32_t w[4]; bf16x8 v; } u;
        u.w[0] = r0[0]; u.w[1] = r1[0]; u.w[2] = r0[1]; u.w[3] = r1[1];
        pb[st] = u.v;
      }

      __builtin_amdgcn_s_setprio(1);
#pragma unroll
      for (int st = 0; st < 2; ++st) {
        lacc = __builtin_amdgcn_mfma_f32_32x32x16_bf16(ones, pb[st], lacc, 0, 0, 0);
#pragma unroll
        for (int nb = 0; nb < 2; ++nb) {
          const bf16x8 vf = *(const bf16x8*)&Vt[cur][(nb * 32 + l31) * DP + kb2 * 32 + st * 16 + hb * 8];
          oacc[nb] = __builtin_amdgcn_mfma_f32_32x32x16_bf16(vf, pb[st], oacc[nb], 0, 0, 0);
        }
      }
      __builtin_amdgcn_s_setprio(0);
    }

    if (havenext) kvwrite(cur ^ 1);
    __syncthreads();
  }

  const float inv = 1.0f / lacc[0];
  u16* Yrow = Y + ((size_t)b * 2048 + qg) * 1024 + h * 64;
#pragma unroll
  for (int nb = 0; nb < 2; ++nb) {
#pragma unroll
    for (int g = 0; g < 4; ++g) {
      ushort4 o;
      o.x = f2bf(oacc[nb][4 * g + 0] * inv);
      o.y = f2bf(oacc[nb][4 * g + 1] * inv);
      o.z = f2bf(oacc[nb][4 * g + 2] * inv);
      o.w = f2bf(oacc[nb][4 * g + 3] * inv);
      *(ushort4*)(Yrow + nb * 32 + g * 8 + hb * 4) = o;
    }
  }
}

// ---------------------------------------------------------------- launch
extern "C" void kernel_launch(void* const* d_in, const int* in_sizes, int n_in,
                              void* d_out, int out_size, void* d_ws,
                              size_t ws_size, hipStream_t stream) {
  const float* x = (const float*)d_in[0];       // [4,2048,1024] fp32
  const float* w_qkv = (const float*)d_in[1];   // [1024,3072] fp32
  const float* w_proj = (const float*)d_in[2];  // [1024,1024] fp32
  float* out = (float*)d_out;                   // [4,2048,1024] fp32

  char* ws = (char*)d_ws;
  u16* xb = (u16*)ws;                          // [8192][1024]  16 MB (dead after QKV GEMM)
  u16* VTw = (u16*)ws;                         // [B,H,D,T]     16 MB (aliases xb)
  u16* wqkvT = (u16*)(ws + 16777216);          // [3072][1024]   6 MB
  u16* wprojT = (u16*)(ws + 23068672);         // [1024][1024]   2 MB
  u16* Qw = (u16*)(ws + 25165824);             // [B,H,T,D]     16 MB
  u16* Kw = (u16*)(ws + 41943040);             // 16 MB
  u16* Vw = (u16*)(ws + 58720256);             // 16 MB
  u16* Yw = (u16*)(ws + 75497472);             // [B*T][C]      16 MB
  if (ws_size < 92274688) return;

  cvt_f32_bf16<<<dim3(8192), dim3(256), 0, stream>>>(x, xb, 8388608);

  dim3 tb(64, 16);
  transpose_cvt<<<dim3(48, 16), tb, 0, stream>>>(w_qkv, wqkvT, 1024, 3072);
  transpose_cvt<<<dim3(16, 16), tb, 0, stream>>>(w_proj, wprojT, 1024, 1024);

  gemm8p<1><<<dim3(12, 64), dim3(512), 0, stream>>>(
      xb, wqkvT, Qw, Kw, Vw, (float*)nullptr, 0, 1024);

  // xb is dead now; build VT in its place.
  transpose_v<<<dim3(32, 64), tb, 0, stream>>>(Vw, VTw);

  attn_fwd<<<dim3(16, 64), dim3(256), 0, stream>>>(Qw, Kw, VTw, Yw);

  gemm8p<0><<<dim3(4, 64), dim3(512), 0, stream>>>(
      Yw, wprojT, (u16*)nullptr, (u16*)nullptr, (u16*)nullptr, out, 1024, 1024);
}